// Round 11
// baseline (29.768 us; speedup 1.0000x reference)
//
#include <hip/hip_runtime.h>
#include <hip/hip_bf16.h>

// out = value @ Wv + bv + key   (softmax over [.,.,1,1] is identically 1 -> ctx == v)
// M=2048, N=1024, K=1024
//
// R10 analysis: single-pass tiling traffic floor ~90MB at grid>=256; LDS/barrier
// machinery costs ~4us extra when 1 block/CU. R11: split-K4 @ 128x128 tiles ->
// 64MB reads, 512 blocks (2/CU, overhead overlapped), partials + fused reduce.
//
// K1 convert: value f32 -> Vb bf16 (64-row tiled+swizzled); Wv -> WvTb bf16 [n][k].
// K2 gemm_splitk: 512 blocks = (bm2 16) x (bn 8) x (kh 4), XCD-swizzled.
//     Block: 128x128 out tile, K-quarter (4 k-tiles of 64). 2-buf LDS (64KB),
//     counted vmcnt, 4 waves (2x2), wave = 64x64 (acc 4x4), scattered f32
//     partial stores (E2: cheap).
// K3 reduce: out = p0+p1+p2+p3 + key + bv, fully coalesced f32x4.
//
// Tile layout (Vb, WvTb): tile (t, kt) = 4096 shorts at (t*16+kt)*4096;
// element (r, kk) at r*64 + ((c ^ (r&7))<<3) + (kk&7), c = kk>>3.

#define M_DIM 2048
#define N_DIM 1024
#define K_DIM 1024

typedef __attribute__((ext_vector_type(8))) short short8;
typedef __attribute__((ext_vector_type(4))) float f32x4;

__device__ inline unsigned rne_bf16(float f) {
    unsigned u = __builtin_bit_cast(unsigned, f);
    return (u + 0x7FFFu + ((u >> 16) & 1u)) >> 16;
}
__device__ inline unsigned pack2(float lo, float hi) {
    return rne_bf16(lo) | (rne_bf16(hi) << 16);
}
__device__ inline void gl_lds16(const short* g, short* l) {
    __builtin_amdgcn_global_load_lds((const __attribute__((address_space(1))) void*)g,
                                     (__attribute__((address_space(3))) void*)l,
                                     16, 0, 0);
}

// ---------------- K1: convert + transpose (proven) ----------------
__global__ __launch_bounds__(256)
void convert_kernel(const float* __restrict__ value, const float* __restrict__ Wv,
                    short* __restrict__ Vb, short* __restrict__ WvTb) {
    __shared__ unsigned tr[64 * 36];
    const int b = blockIdx.x, tid = threadIdx.x;
    if (b < 1024) {
        int g = b * 256 + tid;
        int row = g >> 7, ch = g & 127;
        int kt = ch >> 3, c = ch & 7;
        int tm = row >> 6, r = row & 63;
        const float* p = value + (size_t)row * K_DIM + ch * 8;
        f32x4 a0 = *(const f32x4*)p;
        f32x4 a1 = *(const f32x4*)(p + 4);
        union { short8 s; unsigned u[4]; } o;
        o.u[0] = pack2(a0[0], a0[1]);
        o.u[1] = pack2(a0[2], a0[3]);
        o.u[2] = pack2(a1[0], a1[1]);
        o.u[3] = pack2(a1[2], a1[3]);
        *(short8*)&Vb[(size_t)(tm * 16 + kt) * 4096 + r * 64 + ((c ^ (r & 7)) << 3)] = o.s;
    } else {
        int b2 = b - 1024;
        int tn = b2 & 15, kt = b2 >> 4;
        #pragma unroll
        for (int s = 0; s < 2; ++s) {
            int kp = (tid >> 4) + s * 16;
            int n4 = (tid & 15) * 4;
            const float* bp = Wv + (size_t)(kt * 64 + 2 * kp) * N_DIM + tn * 64 + n4;
            f32x4 b0 = *(const f32x4*)bp;
            f32x4 b1 = *(const f32x4*)(bp + N_DIM);
            #pragma unroll
            for (int m = 0; m < 4; ++m)
                tr[(n4 + m) * 36 + kp] = pack2(b0[m], b1[m]);
        }
        __syncthreads();
        int n = tid >> 2;
        #pragma unroll
        for (int h = 0; h < 2; ++h) {
            int c = (tid & 3) + 4 * h;
            union { short8 s; unsigned u[4]; } o;
            #pragma unroll
            for (int p = 0; p < 4; ++p)
                o.u[p] = tr[n * 36 + c * 4 + p];
            *(short8*)&WvTb[(size_t)(tn * 16 + kt) * 4096 + n * 64 + ((c ^ (n & 7)) << 3)] = o.s;
        }
    }
}

// ---------------- K2: split-K4 128x128 GEMM ----------------
__global__ __launch_bounds__(256)
void gemm_splitk(const short* __restrict__ Vb, const short* __restrict__ WvTb,
                 float* __restrict__ partials) {
    __shared__ __align__(16) short As[2][8192];   // 32 KB (two 64-row subtiles)
    __shared__ __align__(16) short Bs[2][8192];   // 32 KB (two 64-col subtiles)

    const int tid = threadIdx.x, bid = blockIdx.x;
    // XCD swizzle: xcd owns 2 bm-bands x 8 bn x 4 kh = 64 blocks.
    // Per-XCD L2 set: A 2x(128x1024) 512KB + B full 2MB = 2.5MB < 4MB.
    const int xcd = bid & 7, idx = bid >> 3;       // idx 0..63
    const int bm2 = xcd * 2 + (idx >> 5);          // 0..15 (128-row band)
    const int rem = idx & 31;
    const int bn  = rem >> 2;                      // 0..7  (128-col band)
    const int kh  = rem & 3;                       // 0..3  (256-k quarter)
    const int lane = tid & 63, wid = tid >> 6;
    const int wr = wid >> 1, wc = wid & 1;         // wave = 64x64 quadrant

    const short* A0 = Vb   + (size_t)(bm2 * 2)     * 16 * 4096;
    const short* A1 = Vb   + (size_t)(bm2 * 2 + 1) * 16 * 4096;
    const short* B0 = WvTb + (size_t)(bn * 2)      * 16 * 4096;
    const short* B1 = WvTb + (size_t)(bn * 2 + 1)  * 16 * 4096;

    f32x4 acc[4][4] = {};

    auto stage = [&](int buf, int kt) {            // 8 x gl_lds16 (4KB each)
        const size_t o = (size_t)kt * 4096 + tid * 8;
        gl_lds16(A0 + o,        &As[buf][tid * 8]);
        gl_lds16(A0 + o + 2048, &As[buf][2048 + tid * 8]);
        gl_lds16(A1 + o,        &As[buf][4096 + tid * 8]);
        gl_lds16(A1 + o + 2048, &As[buf][6144 + tid * 8]);
        gl_lds16(B0 + o,        &Bs[buf][tid * 8]);
        gl_lds16(B0 + o + 2048, &Bs[buf][2048 + tid * 8]);
        gl_lds16(B1 + o,        &Bs[buf][4096 + tid * 8]);
        gl_lds16(B1 + o + 2048, &Bs[buf][6144 + tid * 8]);
    };

    auto compute = [&](int buf) {
        #pragma unroll
        for (int ks = 0; ks < 2; ++ks) {
            short8 afr[4], bfr[4];
            const int g = ks * 4 + (lane >> 4);
            #pragma unroll
            for (int fm = 0; fm < 4; ++fm) {
                int r = fm * 16 + (lane & 15);     // 0..63 within subtile
                afr[fm] = *(const short8*)&As[buf][wr * 4096 + r * 64 + ((g ^ (r & 7)) << 3)];
            }
            #pragma unroll
            for (int fn = 0; fn < 4; ++fn) {
                int n = fn * 16 + (lane & 15);
                bfr[fn] = *(const short8*)&Bs[buf][wc * 4096 + n * 64 + ((g ^ (n & 7)) << 3)];
            }
            #pragma unroll
            for (int fm = 0; fm < 4; ++fm)
                #pragma unroll
                for (int fn = 0; fn < 4; ++fn)
                    acc[fm][fn] = __builtin_amdgcn_mfma_f32_16x16x32_bf16(
                        afr[fm], bfr[fn], acc[fm][fn], 0, 0, 0);
        }
    };

    const int k0 = kh * 4;                          // this block's 4 k-tiles
    stage(0, k0);
    stage(1, k0 + 1);
    #pragma unroll
    for (int kt = 0; kt < 4; ++kt) {
        if (kt <= 2) asm volatile("s_waitcnt vmcnt(8)" ::: "memory");
        else         asm volatile("s_waitcnt vmcnt(0)" ::: "memory");
        __builtin_amdgcn_s_barrier();
        compute(kt & 1);
        if (kt + 2 < 4) {
            __builtin_amdgcn_s_barrier();           // all waves done with buf
            stage(kt & 1, k0 + kt + 2);
        }
    }

    // partial store (scattered 64B f32 segments -> L2; E2 proved cheap)
    float* pk = partials + (size_t)kh * M_DIM * N_DIM;
    const int row0 = bm2 * 128, col0 = bn * 128;
    const int colW = col0 + wc * 64 + (lane & 15);
    const int rowW = row0 + wr * 64 + (lane >> 4) * 4;
    #pragma unroll
    for (int fm = 0; fm < 4; ++fm)
        #pragma unroll
        for (int fn = 0; fn < 4; ++fn) {
            int col = colW + fn * 16;
            #pragma unroll
            for (int i = 0; i < 4; ++i)
                pk[(size_t)(rowW + fm * 16 + i) * N_DIM + col] = acc[fm][fn][i];
        }
}

// ---------------- K3: reduce + bias + residual (coalesced) ----------------
__global__ __launch_bounds__(256)
void reduce_kernel(const float* __restrict__ partials, const float* __restrict__ key,
                   const float* __restrict__ bv, float* __restrict__ out) {
    const int g = blockIdx.x * 256 + threadIdx.x;   // 0..131071
    const float* p0 = partials;
    const float* p1 = partials + (size_t)1 * M_DIM * N_DIM;
    const float* p2 = partials + (size_t)2 * M_DIM * N_DIM;
    const float* p3 = partials + (size_t)3 * M_DIM * N_DIM;
    #pragma unroll
    for (int it = 0; it < 4; ++it) {
        int q = g + it * 131072;                    // quad index 0..524287
        size_t off = (size_t)q * 4;
        int col4 = (q & 255) * 4;
        f32x4 s = *(const f32x4*)(p0 + off);
        s = s + *(const f32x4*)(p1 + off);
        s = s + *(const f32x4*)(p2 + off);
        s = s + *(const f32x4*)(p3 + off);
        s = s + *(const f32x4*)(key + off);
        s = s + *(const f32x4*)(bv + col4);
        *(f32x4*)(out + off) = s;
    }
}

extern "C" void kernel_launch(void* const* d_in, const int* in_sizes, int n_in,
                              void* d_out, int out_size, void* d_ws, size_t ws_size,
                              hipStream_t stream) {
    // setup_inputs order: 0 query, 1 key, 2 value, 3 Wq, 4 bq, 5 Wk, 6 bk, 7 Wv, 8 bv, 9 U
    const float* key   = (const float*)d_in[1];
    const float* value = (const float*)d_in[2];
    const float* Wv    = (const float*)d_in[7];
    const float* bv    = (const float*)d_in[8];
    float* out = (float*)d_out;

    char* ws = (char*)d_ws;
    short* Vb       = (short*)(ws + 0);            // 4 MB
    short* WvTb     = (short*)(ws + (4 << 20));    // 2 MB
    float* partials = (float*)(ws + (8 << 20));    // 4 x 8 MB f32

    convert_kernel<<<1024 + 256, 256, 0, stream>>>(value, Wv, Vb, WvTb);
    gemm_splitk<<<512, 256, 0, stream>>>(Vb, WvTb, partials);
    reduce_kernel<<<512, 256, 0, stream>>>(partials, key, bv, out);
}

// Round 12
// 21.429 us; speedup vs baseline: 1.3892x; 1.3892x over previous
//
#include <hip/hip_runtime.h>
#include <hip/hip_bf16.h>

// out = value @ Wv + bv + key   (softmax over [.,.,1,1] is identically 1 -> ctx == v)
// M=2048, N=1024, K=1024
//
// SINGLE fused kernel (launch overhead ~4.5us/launch measured R10 vs R11):
//   128x64 tile, 512 threads (8 waves), 2-buffer LDS, reg-staged f32->bf16
//   conversion in the staging path (no convert pre-pass, no ws):
//     - A: value f32, 16 f32/thread -> 8 pack2 -> 2 ds_write_b128 (XOR-swizzled)
//     - B: Wv f32 (k-major), 8 f32/thread (2 k-rows x 4 n) -> pack2 k-pairs ->
//          4 ds_write_b32 at ((n>>1)&7)-swizzled chunks  (R1-verified transpose)
//   Loads issued 2 K-steps ahead (reg double-set); ONE lgkmcnt(0)+s_barrier per
//   K-step (vmcnt never drained in-loop -> loads stay in flight across barriers).
//   key/bv reg-prefetch at kt==13; LDS-transpose epilogue, coalesced f32x4 out.

#define M_DIM 2048
#define N_DIM 1024
#define K_DIM 1024

typedef __attribute__((ext_vector_type(8))) short short8;
typedef __attribute__((ext_vector_type(4))) float f32x4;

__device__ inline unsigned rne_bf16(float f) {
    unsigned u = __builtin_bit_cast(unsigned, f);
    return (u + 0x7FFFu + ((u >> 16) & 1u)) >> 16;
}
__device__ inline unsigned pack2(float lo, float hi) {
    return rne_bf16(lo) | (rne_bf16(hi) << 16);
}

__global__ __launch_bounds__(512)
void fused_gemm(const float* __restrict__ value, const float* __restrict__ Wv,
                const float* __restrict__ key, const float* __restrict__ bv,
                float* __restrict__ out) {
    __shared__ __align__(16) char smem[49152];
    short (*As)[8192] = (short (*)[8192])smem;             // 2 x 16 KB (128r x 64k bf16)
    short (*Bs)[4096] = (short (*)[4096])(smem + 32768);   // 2 x 8 KB  (64n x 64k bf16)

    const int tid = threadIdx.x, bid = blockIdx.x;
    // XCD swizzle: xcd owns 2 bm2-bands x 16 bn = 32 blocks.
    const int xcd = bid & 7, idx = bid >> 3;
    const int bm2 = xcd * 2 + (idx >> 4);   // 0..15 (128-row band)
    const int bn  = idx & 15;               // 0..15 (64-col band)
    const int row0 = bm2 * 128, col0 = bn * 64;
    const int lane = tid & 63, wid = tid >> 6;
    const int wr = wid >> 1, wc = wid & 1;  // wave: rows wr*32..+31, cols wc*32..+31

    // ---- staging coordinates
    const int rowA = tid >> 2;              // 0..127
    const int kq   = tid & 3;               // which 16-f32 slab of the 64-k tile
    const float* aptr = value + (size_t)(row0 + rowA) * K_DIM + kq * 16;
    const int kp = tid >> 4;                // 0..31 (k-pair within tile)
    const int n4 = (tid & 15) * 4;
    const float* bptr = Wv + (size_t)(2 * kp) * N_DIM + col0 + n4;

    f32x4 sa[2][4];   // two reg sets (tile parity), 16 A f32 each
    f32x4 sb[2][2];   // 8 B f32 each (k rows 2kp, 2kp+1)

    auto loadT = [&](int s, int kt) {
        const float* ap = aptr + kt * 64;
        sa[s][0] = *(const f32x4*)(ap + 0);
        sa[s][1] = *(const f32x4*)(ap + 4);
        sa[s][2] = *(const f32x4*)(ap + 8);
        sa[s][3] = *(const f32x4*)(ap + 12);
        const float* bp = bptr + (size_t)kt * 64 * N_DIM;
        sb[s][0] = *(const f32x4*)bp;
        sb[s][1] = *(const f32x4*)(bp + N_DIM);
    };

    auto cvtWrite = [&](int s, int buf) {
        union { short8 v; unsigned u[4]; } c0, c1;
        c0.u[0] = pack2(sa[s][0][0], sa[s][0][1]);
        c0.u[1] = pack2(sa[s][0][2], sa[s][0][3]);
        c0.u[2] = pack2(sa[s][1][0], sa[s][1][1]);
        c0.u[3] = pack2(sa[s][1][2], sa[s][1][3]);
        c1.u[0] = pack2(sa[s][2][0], sa[s][2][1]);
        c1.u[1] = pack2(sa[s][2][2], sa[s][2][3]);
        c1.u[2] = pack2(sa[s][3][0], sa[s][3][1]);
        c1.u[3] = pack2(sa[s][3][2], sa[s][3][3]);
        const int sw = rowA & 7;
        *(short8*)&As[buf][rowA * 64 + (((kq * 2)     ^ sw) << 3)] = c0.v;
        *(short8*)&As[buf][rowA * 64 + (((kq * 2 + 1) ^ sw) << 3)] = c1.v;
        unsigned* bu = (unsigned*)&Bs[buf][0];
        #pragma unroll
        for (int m = 0; m < 4; ++m) {
            unsigned u = pack2(sb[s][0][m], sb[s][1][m]);  // (k even, k odd)
            int n = n4 + m;
            int chB = (kp >> 2) ^ ((n >> 1) & 7);
            bu[n * 32 + (chB << 2) + (kp & 3)] = u;
        }
    };

    f32x4 acc[2][2] = {};
    auto compute = [&](int buf) {
        #pragma unroll
        for (int ks = 0; ks < 2; ++ks) {
            short8 afr[2], bfr[2];
            const int g = ks * 4 + (lane >> 4);
            #pragma unroll
            for (int fm = 0; fm < 2; ++fm) {
                int r = wr * 32 + fm * 16 + (lane & 15);
                afr[fm] = *(const short8*)&As[buf][r * 64 + ((g ^ (r & 7)) << 3)];
            }
            #pragma unroll
            for (int fn = 0; fn < 2; ++fn) {
                int n = wc * 32 + fn * 16 + (lane & 15);
                bfr[fn] = *(const short8*)&Bs[buf][n * 64 + ((g ^ ((n >> 1) & 7)) << 3)];
            }
            #pragma unroll
            for (int fm = 0; fm < 2; ++fm)
                #pragma unroll
                for (int fn = 0; fn < 2; ++fn)
                    acc[fm][fn] = __builtin_amdgcn_mfma_f32_16x16x32_bf16(
                        afr[fm], bfr[fn], acc[fm][fn], 0, 0, 0);
        }
    };

    // epilogue prefetch regs
    f32x4 kr[4];
    f32x4 br;
    const int rE = tid >> 4;                // 0..31
    const int cE = (tid & 15) * 4;          // 0..60

    // ---- prologue: T0,T1 in regs; T0 -> LDS buf0
    loadT(0, 0);
    loadT(1, 1);
    cvtWrite(0, 0);
    asm volatile("s_waitcnt lgkmcnt(0)" ::: "memory");
    __builtin_amdgcn_s_barrier();
    __builtin_amdgcn_sched_barrier(0);

    // ---- main loop: one barrier per K-step; vmcnt never drained (compiler
    //      inserts precise per-load waits for the reg-staged f32 loads).
    #pragma unroll
    for (int kt = 0; kt < 16; ++kt) {
        const int buf = kt & 1;
        if (kt + 2 < 16) loadT(buf, kt + 2);        // set (kt&1) freed at step kt-1
        compute(buf);                               // tile kt from LDS
        if (kt + 1 < 16) cvtWrite((kt + 1) & 1, buf ^ 1);
        if (kt == 13) {                             // key/bv prefetch (HBM-cold)
            #pragma unroll
            for (int it = 0; it < 4; ++it)
                kr[it] = *(const f32x4*)&key[(size_t)(row0 + it * 32 + rE) * N_DIM + col0 + cE];
            br = *(const f32x4*)&bv[col0 + cE];
        }
        asm volatile("s_waitcnt lgkmcnt(0)" ::: "memory");
        __builtin_amdgcn_s_barrier();
        __builtin_amdgcn_sched_barrier(0);
    }

    // ---- epilogue: acc -> LDS transpose (reuses all smem) -> coalesced f32x4
    float* T = (float*)smem;                // 128 x 68 f32 = 34.8 KB <= 48 KB
    #pragma unroll
    for (int fm = 0; fm < 2; ++fm)
        #pragma unroll
        for (int fn = 0; fn < 2; ++fn) {
            int c = wc * 32 + fn * 16 + (lane & 15);
            #pragma unroll
            for (int i = 0; i < 4; ++i) {
                int r = wr * 32 + fm * 16 + (lane >> 4) * 4 + i;
                T[r * 68 + c] = acc[fm][fn][i];
            }
        }
    asm volatile("s_waitcnt lgkmcnt(0)" ::: "memory");
    __builtin_amdgcn_s_barrier();
    #pragma unroll
    for (int it = 0; it < 4; ++it) {
        int r = it * 32 + rE;
        f32x4 vv = *(f32x4*)&T[r * 68 + cE];
        vv = vv + kr[it] + br;
        *(f32x4*)&out[(size_t)(row0 + r) * N_DIM + col0 + cE] = vv;
    }
}

extern "C" void kernel_launch(void* const* d_in, const int* in_sizes, int n_in,
                              void* d_out, int out_size, void* d_ws, size_t ws_size,
                              hipStream_t stream) {
    // setup_inputs order: 0 query, 1 key, 2 value, 3 Wq, 4 bq, 5 Wk, 6 bk, 7 Wv, 8 bv, 9 U
    const float* key   = (const float*)d_in[1];
    const float* value = (const float*)d_in[2];
    const float* Wv    = (const float*)d_in[7];
    const float* bv    = (const float*)d_in[8];
    float* out = (float*)d_out;

    fused_gemm<<<256, 512, 0, stream>>>(value, Wv, key, bv, out);
}